// Round 6
// baseline (205.744 us; speedup 1.0000x reference)
//
#include <hip/hip_runtime.h>
#include <hip/hip_bf16.h>

typedef unsigned short u16;
typedef unsigned int   u32;
typedef unsigned long long u64;
typedef __attribute__((ext_vector_type(8))) short short8;   // 8 bf16 (4 VGPRs)
typedef __attribute__((ext_vector_type(4))) float float4v;  // 4 fp32 acc

#define N 8192
#define D 128
#define C 1000
#define TILE 128
#define NW64 (N / 64)  // 128 packed words per class row
#define JQ 4           // j-tiles per block
#define GRIDY 16       // j-splits; GRIDY*JQ = 64 tiles
#define NBLK ((N / TILE) * GRIDY)   // 1024 cc_main blocks
#define JW (JQ * 2)    // mask words per row per block
#define LOG2E 1.44269504088896340736f

// ---------------------------------------------------------------------------
// Kernel 1 (prep): fused pack + norm.
// R17: pack loads vectorized to float4 (16B/lane, G13); scalar fallback for
// the lt==15 boundary (cols 960..1023 vs C=1000). Also zeroes the cc_main
// completion counter used by the fused loss tail.
// ---------------------------------------------------------------------------
__global__ void prep_kernel(const float* __restrict__ nm, u64* __restrict__ packed,
                            const float* __restrict__ x, const float* __restrict__ pr,
                            u16* __restrict__ xnb, float* __restrict__ p_out,
                            float* __restrict__ den, float* __restrict__ num,
                            int* __restrict__ ctr,
                            const float* __restrict__ tp, const float* __restrict__ mp) {
    __shared__ u32 Ls[64 * 65];
    const int bid  = blockIdx.x;
    const int lane = threadIdx.x & 63;
    const int wv   = threadIdx.x >> 6;

    if (bid < 2048) {
        // ---- pack part: 64x64 tile through LDS, column ballots ----
        const int jt = bid & 127;
        const int lt = bid >> 7;
        const int j0 = jt * 64;
        const int l0 = lt * 64;

        if (lt < 15) {
            // vector path: thread t -> row it*16 + (t>>4), 4 cols at (t&15)*4.
            // Alignment: row stride 1000 floats = 4000 B (16B multiple), l0%4==0.
            const int tid = threadIdx.x;
            #pragma unroll
            for (int it = 0; it < 4; it++) {
                const int r  = it * 16 + (tid >> 4);
                const int c0 = (tid & 15) * 4;
                const float4 v = *(const float4*)(nm + (size_t)(j0 + r) * C + l0 + c0);
                Ls[r * 65 + c0 + 0] = (v.x > 0.5f) ? 1u : 0u;
                Ls[r * 65 + c0 + 1] = (v.y > 0.5f) ? 1u : 0u;
                Ls[r * 65 + c0 + 2] = (v.z > 0.5f) ? 1u : 0u;
                Ls[r * 65 + c0 + 3] = (v.w > 0.5f) ? 1u : 0u;
            }
        } else {
            const int l  = l0 + lane;
            const bool lv = l < C;
            #pragma unroll
            for (int rr = 0; rr < 16; rr++) {
                const int r = wv * 16 + rr;
                float v = lv ? nm[(size_t)(j0 + r) * C + l] : 0.0f;
                Ls[r * 65 + lane] = (v > 0.5f) ? 1u : 0u;
            }
        }
        __syncthreads();
        #pragma unroll
        for (int cc = 0; cc < 16; cc++) {
            const int c = wv * 16 + cc;
            u64 m = __ballot(Ls[lane * 65 + c] != 0u);
            if (lane == 0 && (lt * 64 + c) < C)
                packed[(size_t)(lt * 64 + c) * NW64 + jt] = m;
        }
    } else {
        // ---- norm part: one wave per row ----
        if (bid == 2048 && threadIdx.x == 0) ctr[0] = 0;
        const int row = (bid - 2048) * 4 + wv;
        const float2* xr  = (const float2*)(x  + (size_t)row * D);
        const float2* prr = (const float2*)(pr + (size_t)row * D);
        float2 xv = xr[lane];
        float2 pv = prr[lane];

        float sx  = xv.x * xv.x + xv.y * xv.y;
        float sp  = pv.x * pv.x + pv.y * pv.y;
        float sxp = xv.x * pv.x + xv.y * pv.y;
        #pragma unroll
        for (int off = 32; off; off >>= 1) {
            sx  += __shfl_xor(sx,  off);
            sp  += __shfl_xor(sp,  off);
            sxp += __shfl_xor(sxp, off);
        }
        float nx = fmaxf(sqrtf(sx), 1e-8f);
        float np = fmaxf(sqrtf(sp), 1e-8f);
        float inv = 1.0f / nx;

        __hip_bfloat16 b0 = __float2bfloat16(xv.x * inv);
        __hip_bfloat16 b1 = __float2bfloat16(xv.y * inv);
        ((__hip_bfloat162*)xnb)[(size_t)row * 64 + lane] = __halves2bfloat162(b0, b1);

        if (lane == 0) {
            float T = tp[0], M = mp[0];
            p_out[row] = __expf((sxp / (nx * np) - M) / T);
            den[row] = 0.0f;
            num[row] = 0.0f;
        }
    }
}

// ---------------------------------------------------------------------------
// Kernel 2 (cc_main): R17 — half-tile ping-pong staging + fused loss tail.
// R16 post-mortem: cc_main ~34us vs ~11us LDS-pipe floor; the q-loop's
// [barrier; stage-issue; barrier(full drain)] exposes staging latency
// between back-to-back barriers. Fix (T3-minimum): Bs split into two 16KB
// halves; each phase ISSUES the other half's stage, COMPUTES the current
// half, then __syncthreads (drain happens AFTER ~1us of compute -> hidden).
// Same LDS total (40960B, 4 blocks/CU), same epi/mfma code (R15-verified),
// lb(256,2) (R5-proven spill-free, ~96 core VGPRs).
// Loss fused via last-block pattern: threadfence + agent-scope ctr; last
// block reads p/den/num with agent-scope atomic loads (per-XCD L2 safety).
// ---------------------------------------------------------------------------
#define AS1 __attribute__((address_space(1)))
#define AS3 __attribute__((address_space(3)))

static __device__ __forceinline__ void load_lds16(const u16* g, u16* l) {
    __builtin_amdgcn_global_load_lds((const AS1 u32*)(const void*)g,
                                     (AS3 u32*)(void*)l, 16, 0, 0);
}

template <bool RELOAD>
__device__ __forceinline__ void mfma_chunk(float4v (&acc)[2][2], const short8 (&a_f)[4][2],
                                           short8 (&bc)[4][2], const u16* Bnext,
                                           const int (&koff)[4]) {
    #pragma unroll
    for (int a = 0; a < 2; a++)
        #pragma unroll
        for (int b = 0; b < 2; b++)
            acc[a][b] = (float4v){0.f, 0.f, 0.f, 0.f};
    #pragma unroll
    for (int kk = 0; kk < 4; kk++) {
        #pragma unroll
        for (int tm = 0; tm < 2; tm++)
            #pragma unroll
            for (int tn = 0; tn < 2; tn++)
                acc[tm][tn] = __builtin_amdgcn_mfma_f32_16x16x32_bf16(
                    a_f[kk][tm], bc[kk][tn], acc[tm][tn], 0, 0, 0);
        if (RELOAD) {
            #pragma unroll
            for (int tn = 0; tn < 2; tn++)
                bc[kk][tn] = *(const short8*)(Bnext + tn * 2048 + koff[kk]);
        }
    }
}

// CI = global chunk index (0..3): local j = CI*32 + tn*16 + m0.
template <bool DIAG, int CI>
__device__ __forceinline__ void epi_chunk(const float4v (&acc)[2][2], const u64* __restrict__ Ms,
                                          float (&dacc)[2][4], float (&nacc)[2][4],
                                          int wv, int kq, int m0,
                                          int ibase, int jbase, int q,
                                          float kA2, float kB2) {
    #pragma unroll
    for (int tm = 0; tm < 2; tm++) {
        #pragma unroll
        for (int r = 0; r < 4; r++) {
            const int lrow = wv * 32 + tm * 16 + kq * 4 + r;
            const u64 ws = Ms[lrow * JW + q * 2 + (CI >> 1)] >> m0;
            const int gi = ibase + lrow;
            #pragma unroll
            for (int tn = 0; tn < 2; tn++) {
                float e = __builtin_amdgcn_exp2f(fmaf(acc[tm][tn][r], kA2, kB2));
                if (DIAG) {
                    const int gj = jbase + CI * 32 + tn * 16 + m0;
                    if (gi == gj) e = 0.0f;
                }
                dacc[tm][r] += e;
                const u32 bit = (u32)(ws >> (((CI & 1) * 2 + tn) * 16)) & 1u;
                nacc[tm][r] = fmaf((float)bit, e, nacc[tm][r]);
            }
        }
    }
}

// Compute one half (chunks H*2, H*2+1) from LDS half base LBh.
template <bool DIAG, int H>
__device__ __forceinline__ void phase_compute(float4v (&acc)[2][2], const short8 (&a_f)[4][2],
                                              short8 (&bc)[4][2], const u16* LBh,
                                              const int (&koff)[4], const u64* __restrict__ Ms,
                                              float (&dacc)[2][4], float (&nacc)[2][4],
                                              int wv, int kq, int m0,
                                              int ibase, int jbase, int q,
                                              float kA2, float kB2) {
    #pragma unroll
    for (int kk = 0; kk < 4; kk++)
        #pragma unroll
        for (int tn = 0; tn < 2; tn++)
            bc[kk][tn] = *(const short8*)(LBh + tn * 2048 + koff[kk]);
    mfma_chunk<true>(acc, a_f, bc, LBh + 4096, koff);
    epi_chunk<DIAG, H * 2 + 0>(acc, Ms, dacc, nacc, wv, kq, m0, ibase, jbase, q, kA2, kB2);
    mfma_chunk<false>(acc, a_f, bc, LBh, koff);
    epi_chunk<DIAG, H * 2 + 1>(acc, Ms, dacc, nacc, wv, kq, m0, ibase, jbase, q, kA2, kB2);
}

__global__ __launch_bounds__(256, 2)
void cc_main(const u16* __restrict__ xnb, const int* __restrict__ labels,
             const u64* __restrict__ packed,
             float* __restrict__ den, float* __restrict__ num,
             const float* __restrict__ p_arr, float* __restrict__ out,
             int* __restrict__ ctr,
             const float* __restrict__ tp, const float* __restrict__ mp) {
    __shared__ u16 Bs[2][64 * D];     // 2 x 16384 B (ping-pong halves)
    __shared__ u64 Ms[TILE * JW];     // 8192 B   -> total 40960 B, 4 blk/CU

    const int tid  = threadIdx.x;
    const int lane = tid & 63;
    const int wv   = tid >> 6;        // wave = 32 rows x 128 cols
    const int m0   = lane & 15;
    const int kq   = lane >> 4;
    const int ibase  = blockIdx.x * TILE;
    const int jsplit = blockIdx.y;
    const int jt0    = jsplit * JQ;

    const float T = tp[0];
    const float M = mp[0];
    const float kA2 = LOG2E / T;
    const float kB2 = -M * LOG2E / T;

    // A fragments first (independent loads, overlap the Ms gather latency)
    const u16* Alane = xnb + (size_t)(ibase + wv * 32 + m0) * D + kq * 8;
    short8 a_f[4][2];
    #pragma unroll
    for (int kk = 0; kk < 4; kk++)
        #pragma unroll
        for (int tm = 0; tm < 2; tm++)
            a_f[kk][tm] = *(const short8*)(Alane + tm * (16 * D) + kk * 32);

    // stage mask words: 128 rows x 8 words for this j-split
    #pragma unroll
    for (int t = 0; t < 4; t++) {
        const int idx = t * 256 + tid;
        const int row = idx >> 3, h = idx & 7;
        const int lab = labels[ibase + row];
        Ms[idx] = packed[(size_t)lab * NW64 + jt0 * 2 + h];
    }

    // --- staging geometry (global source pre-swizzled; LDS linear) ---
    const int srow  = wv * 4 + (lane >> 4);               // row base within 16-row group
    const int sunit = (lane & 15) ^ (srow & 7);           // swizzled source unit
    const u16* Bsrc = xnb + (size_t)srow * D + sunit * 8;
    u16* Dst0 = &Bs[0][0] + wv * 512;                     // wave-uniform
    u16* Dst1 = &Bs[1][0] + wv * 512;

    // --- read geometry ---
    const int swz7 = m0 & 7;
    int koff[4];
    #pragma unroll
    for (int kk = 0; kk < 4; kk++) koff[kk] = ((kq + kk * 4) ^ swz7) * 8;
    const u16* LB0 = &Bs[0][0] + m0 * 128;
    const u16* LB1 = &Bs[1][0] + m0 * 128;

    float dacc[2][4] = {};
    float nacc[2][4] = {};
    float4v acc[2][2];
    short8 bc[4][2];

    // prologue: stage H0(q=0); drain (only exposed stage latency, once)
    {
        const u16* sq = Bsrc + (size_t)(jt0 * TILE) * D;
        #pragma unroll
        for (int rnd = 0; rnd < 4; rnd++)
            load_lds16(sq + rnd * 16 * D, Dst0 + rnd * 2048);
    }
    __syncthreads();

    for (int q = 0; q < JQ; q++) {
        const int jt = jt0 + q;
        const int jbase = jt * TILE;
        const bool diag = (jt == blockIdx.x);

        // phase A: issue stage H1(q); compute H0 from Bs[0]
        {
            const u16* sq = Bsrc + (size_t)(jbase + 64) * D;
            #pragma unroll
            for (int rnd = 0; rnd < 4; rnd++)
                load_lds16(sq + rnd * 16 * D, Dst1 + rnd * 2048);
        }
        if (diag) phase_compute<true , 0>(acc, a_f, bc, LB0, koff, Ms, dacc, nacc, wv, kq, m0, ibase, jbase, q, kA2, kB2);
        else      phase_compute<false, 0>(acc, a_f, bc, LB0, koff, Ms, dacc, nacc, wv, kq, m0, ibase, jbase, q, kA2, kB2);
        __syncthreads();   // drains own H1 loads (landed during compute)

        // phase B: issue stage H0(q+1); compute H1 from Bs[1]
        if (q + 1 < JQ) {
            const u16* sq = Bsrc + (size_t)((jbase + TILE) * D);
            #pragma unroll
            for (int rnd = 0; rnd < 4; rnd++)
                load_lds16(sq + rnd * 16 * D, Dst0 + rnd * 2048);
        }
        if (diag) phase_compute<true , 1>(acc, a_f, bc, LB1, koff, Ms, dacc, nacc, wv, kq, m0, ibase, jbase, q, kA2, kB2);
        else      phase_compute<false, 1>(acc, a_f, bc, LB1, koff, Ms, dacc, nacc, wv, kq, m0, ibase, jbase, q, kA2, kB2);
        __syncthreads();
    }

    // reduce across the 16 column-lanes, then atomics
    #pragma unroll
    for (int tm = 0; tm < 2; tm++) {
        #pragma unroll
        for (int r = 0; r < 4; r++) {
            float d = dacc[tm][r], n = nacc[tm][r];
            #pragma unroll
            for (int off = 1; off < 16; off <<= 1) {
                d += __shfl_xor(d, off);
                n += __shfl_xor(n, off);
            }
            if (m0 == 0) {
                const int gi = ibase + wv * 32 + tm * 16 + kq * 4 + r;
                atomicAdd(&den[gi], d);
                atomicAdd(&num[gi], n);
            }
        }
    }

    // ---- fused loss tail: last block computes the final scalar ----
    __threadfence();                      // release this block's den/num atomics
    __syncthreads();                      // all waves done reading Ms
    if (tid == 0) {
        int old = __hip_atomic_fetch_add(ctr, 1, __ATOMIC_ACQ_REL, __HIP_MEMORY_SCOPE_AGENT);
        *(int*)&Ms[0] = (old == NBLK - 1) ? 1 : 0;
    }
    __syncthreads();
    if (*(int*)&Ms[0]) {
        float s = 0.0f;
        #pragma unroll
        for (int t = 0; t < N / 256; t++) {
            const int i = t * 256 + tid;
            float pi = __hip_atomic_load(p_arr + i, __ATOMIC_RELAXED, __HIP_MEMORY_SCOPE_AGENT);
            float d  = __hip_atomic_load(den + i,  __ATOMIC_RELAXED, __HIP_MEMORY_SCOPE_AGENT);
            float n  = __hip_atomic_load(num + i,  __ATOMIC_RELAXED, __HIP_MEMORY_SCOPE_AGENT);
            s += -__logf(T * (pi + n) / (pi + d));
        }
        #pragma unroll
        for (int off = 32; off; off >>= 1) s += __shfl_xor(s, off);
        float* red = (float*)&Bs[0][0];
        if (lane == 0) red[wv] = s;
        __syncthreads();
        if (tid == 0) out[0] = (red[0] + red[1] + red[2] + red[3]) / (float)N;
    }
}

// ---------------------------------------------------------------------------
extern "C" void kernel_launch(void* const* d_in, const int* in_sizes, int n_in,
                              void* d_out, int out_size, void* d_ws, size_t ws_size,
                              hipStream_t stream) {
    (void)in_sizes; (void)n_in; (void)out_size; (void)ws_size;
    const float* inst   = (const float*)d_in[0];
    const float* proxy  = (const float*)d_in[1];
    const float* nm     = (const float*)d_in[2];
    const int*   labels = (const int*)d_in[3];
    const float* temp   = (const float*)d_in[4];
    const float* marg   = (const float*)d_in[5];
    float* out = (float*)d_out;

    char* ws = (char*)d_ws;
    u16*   xnb    = (u16*)ws;                         // N*D*2      = 2,097,152 B
    float* p_arr  = (float*)(ws + 2097152);           // N*4        = 32,768 B
    u64*   packed = (u64*)(ws + 2129920);             // C*128*8    = 1,024,000 B
    float* den    = (float*)(ws + 3153920);           // N*4
    float* num    = (float*)(ws + 3186688);           // N*4
    int*   ctr    = (int*)(ws + 3219456);             // 4 B

    prep_kernel<<<4096, 256, 0, stream>>>(nm, packed, inst, proxy, xnb, p_arr,
                                          den, num, ctr, temp, marg);
    cc_main<<<dim3(N / TILE, GRIDY), 256, 0, stream>>>(xnb, labels, packed, den, num,
                                                       p_arr, out, ctr, temp, marg);
}

// Round 7
// 125.331 us; speedup vs baseline: 1.6416x; 1.6416x over previous
//
#include <hip/hip_runtime.h>
#include <hip/hip_bf16.h>

typedef unsigned short u16;
typedef unsigned int   u32;
typedef unsigned long long u64;
typedef __attribute__((ext_vector_type(8))) short short8;   // 8 bf16 (4 VGPRs)
typedef __attribute__((ext_vector_type(4))) float float4v;  // 4 fp32 acc

#define N 8192
#define D 128
#define C 1000
#define TILE 128
#define NW64 (N / 64)  // 128 packed words per class row
#define JQ 4           // j-tiles per block
#define GRIDY 16       // j-splits; GRIDY*JQ = 64 tiles
#define JW (JQ * 2)    // mask words per row per block
#define LOG2E 1.44269504088896340736f

// ---------------------------------------------------------------------------
// Kernel 1 (prep): fused pack + norm.
// R18: pack loads float4-vectorized (16B/lane, G13; proven correct in R17);
// scalar fallback for the lt==15 boundary (cols 960..1023 vs C=1000).
// ---------------------------------------------------------------------------
__global__ void prep_kernel(const float* __restrict__ nm, u64* __restrict__ packed,
                            const float* __restrict__ x, const float* __restrict__ pr,
                            u16* __restrict__ xnb, float* __restrict__ p_out,
                            float* __restrict__ den, float* __restrict__ num,
                            const float* __restrict__ tp, const float* __restrict__ mp) {
    __shared__ u32 Ls[64 * 65];
    const int bid  = blockIdx.x;
    const int lane = threadIdx.x & 63;
    const int wv   = threadIdx.x >> 6;

    if (bid < 2048) {
        // ---- pack part: 64x64 tile through LDS, column ballots ----
        const int jt = bid & 127;
        const int lt = bid >> 7;
        const int j0 = jt * 64;
        const int l0 = lt * 64;

        if (lt < 15) {
            // vector path: thread t -> row it*16 + (t>>4), 4 cols at (t&15)*4.
            // Alignment: row stride 1000 floats = 4000 B (16B multiple), l0%4==0.
            const int tid = threadIdx.x;
            #pragma unroll
            for (int it = 0; it < 4; it++) {
                const int r  = it * 16 + (tid >> 4);
                const int c0 = (tid & 15) * 4;
                const float4 v = *(const float4*)(nm + (size_t)(j0 + r) * C + l0 + c0);
                Ls[r * 65 + c0 + 0] = (v.x > 0.5f) ? 1u : 0u;
                Ls[r * 65 + c0 + 1] = (v.y > 0.5f) ? 1u : 0u;
                Ls[r * 65 + c0 + 2] = (v.z > 0.5f) ? 1u : 0u;
                Ls[r * 65 + c0 + 3] = (v.w > 0.5f) ? 1u : 0u;
            }
        } else {
            const int l  = l0 + lane;
            const bool lv = l < C;
            #pragma unroll
            for (int rr = 0; rr < 16; rr++) {
                const int r = wv * 16 + rr;
                float v = lv ? nm[(size_t)(j0 + r) * C + l] : 0.0f;
                Ls[r * 65 + lane] = (v > 0.5f) ? 1u : 0u;
            }
        }
        __syncthreads();
        #pragma unroll
        for (int cc = 0; cc < 16; cc++) {
            const int c = wv * 16 + cc;
            u64 m = __ballot(Ls[lane * 65 + c] != 0u);
            if (lane == 0 && (lt * 64 + c) < C)
                packed[(size_t)(lt * 64 + c) * NW64 + jt] = m;
        }
    } else {
        // ---- norm part: one wave per row ----
        const int row = (bid - 2048) * 4 + wv;
        const float2* xr  = (const float2*)(x  + (size_t)row * D);
        const float2* prr = (const float2*)(pr + (size_t)row * D);
        float2 xv = xr[lane];
        float2 pv = prr[lane];

        float sx  = xv.x * xv.x + xv.y * xv.y;
        float sp  = pv.x * pv.x + pv.y * pv.y;
        float sxp = xv.x * pv.x + xv.y * pv.y;
        #pragma unroll
        for (int off = 32; off; off >>= 1) {
            sx  += __shfl_xor(sx,  off);
            sp  += __shfl_xor(sp,  off);
            sxp += __shfl_xor(sxp, off);
        }
        float nx = fmaxf(sqrtf(sx), 1e-8f);
        float np = fmaxf(sqrtf(sp), 1e-8f);
        float inv = 1.0f / nx;

        __hip_bfloat16 b0 = __float2bfloat16(xv.x * inv);
        __hip_bfloat16 b1 = __float2bfloat16(xv.y * inv);
        ((__hip_bfloat162*)xnb)[(size_t)row * 64 + lane] = __halves2bfloat162(b0, b1);

        if (lane == 0) {
            float T = tp[0], M = mp[0];
            p_out[row] = __expf((sxp / (nx * np) - M) / T);
            den[row] = 0.0f;
            num[row] = 0.0f;
        }
    }
}

// ---------------------------------------------------------------------------
// Kernel 2 (cc_main): R18 — exact revert to the R16 structure (best measured:
// ~33us, total 126.5). R17 post-mortem: half-tile ping-pong staging collapsed
// per-wave throughput AND residency (occupancy 33->17.6, all pipes idle) —
// hipcc cannot disambiguate in-flight global_load_lds writes (raw AS3 ptr)
// from ds_reads of the other buffer, so it inserts vmcnt(0) inside every
// phase; source-level pipelining of global_load_lds is compiler-defeated
// (guide Common-mistake #5). The barrier-drain staging below is the proven
// structure: stage whole 32KB tile, one drain per q shared by all waves.
// lb(256,2) is load-bearing (R4: arg=4 halves the VGPR cap -> 115MB spill).
// ---------------------------------------------------------------------------
#define AS1 __attribute__((address_space(1)))
#define AS3 __attribute__((address_space(3)))

static __device__ __forceinline__ void load_lds16(const u16* g, u16* l) {
    __builtin_amdgcn_global_load_lds((const AS1 u32*)(const void*)g,
                                     (AS3 u32*)(void*)l, 16, 0, 0);
}

template <bool RELOAD>
__device__ __forceinline__ void mfma_chunk(float4v (&acc)[2][2], const short8 (&a_f)[4][2],
                                           short8 (&bc)[4][2], const u16* Bnext,
                                           const int (&koff)[4]) {
    #pragma unroll
    for (int a = 0; a < 2; a++)
        #pragma unroll
        for (int b = 0; b < 2; b++)
            acc[a][b] = (float4v){0.f, 0.f, 0.f, 0.f};
    #pragma unroll
    for (int kk = 0; kk < 4; kk++) {
        #pragma unroll
        for (int tm = 0; tm < 2; tm++)
            #pragma unroll
            for (int tn = 0; tn < 2; tn++)
                acc[tm][tn] = __builtin_amdgcn_mfma_f32_16x16x32_bf16(
                    a_f[kk][tm], bc[kk][tn], acc[tm][tn], 0, 0, 0);
        if (RELOAD) {
            #pragma unroll
            for (int tn = 0; tn < 2; tn++)
                bc[kk][tn] = *(const short8*)(Bnext + tn * 2048 + koff[kk]);
        }
    }
}

// CI = compile-time chunk index (0..3): local j = CI*32 + tn*16 + m0.
template <bool DIAG, int CI>
__device__ __forceinline__ void epi_chunk(const float4v (&acc)[2][2], const u64* __restrict__ Ms,
                                          float (&dacc)[2][4], float (&nacc)[2][4],
                                          int wv, int kq, int m0,
                                          int ibase, int jbase, int q,
                                          float kA2, float kB2) {
    #pragma unroll
    for (int tm = 0; tm < 2; tm++) {
        #pragma unroll
        for (int r = 0; r < 4; r++) {
            const int lrow = wv * 32 + tm * 16 + kq * 4 + r;
            const u64 ws = Ms[lrow * JW + q * 2 + (CI >> 1)] >> m0;
            const int gi = ibase + lrow;
            #pragma unroll
            for (int tn = 0; tn < 2; tn++) {
                float e = __builtin_amdgcn_exp2f(fmaf(acc[tm][tn][r], kA2, kB2));
                if (DIAG) {
                    const int gj = jbase + CI * 32 + tn * 16 + m0;
                    if (gi == gj) e = 0.0f;
                }
                dacc[tm][r] += e;
                const u32 bit = (u32)(ws >> (((CI & 1) * 2 + tn) * 16)) & 1u;
                nacc[tm][r] = fmaf((float)bit, e, nacc[tm][r]);
            }
        }
    }
}

__global__ __launch_bounds__(256, 2)
void cc_main(const u16* __restrict__ xnb, const int* __restrict__ labels,
             const u64* __restrict__ packed,
             float* __restrict__ den, float* __restrict__ num,
             const float* __restrict__ tp, const float* __restrict__ mp) {
    __shared__ u16 Bs[TILE * D];      // 32768 B, linear (swizzle in addresses)
    __shared__ u64 Ms[TILE * JW];     // 8192 B

    const int tid  = threadIdx.x;
    const int lane = tid & 63;
    const int wv   = tid >> 6;        // wave = 32 rows x 128 cols
    const int m0   = lane & 15;
    const int kq   = lane >> 4;
    const int ibase  = blockIdx.x * TILE;
    const int jsplit = blockIdx.y;
    const int jt0    = jsplit * JQ;

    const float T = tp[0];
    const float M = mp[0];
    const float kA2 = LOG2E / T;
    const float kB2 = -M * LOG2E / T;

    // stage mask words: 128 rows x 8 words for this j-split
    #pragma unroll
    for (int t = 0; t < 4; t++) {
        const int idx = t * 256 + tid;
        const int row = idx >> 3, h = idx & 7;
        const int lab = labels[ibase + row];
        Ms[idx] = packed[(size_t)lab * NW64 + jt0 * 2 + h];
    }

    // A fragments: 32 rows/wave, loop-invariant, register-resident (32 VGPR).
    const u16* Alane = xnb + (size_t)(ibase + wv * 32 + m0) * D + kq * 8;
    short8 a_f[4][2];
    #pragma unroll
    for (int kk = 0; kk < 4; kk++)
        #pragma unroll
        for (int tm = 0; tm < 2; tm++)
            a_f[kk][tm] = *(const short8*)(Alane + tm * (16 * D) + kk * 32);

    // --- staging geometry (global source pre-swizzled; LDS linear) ---
    // LDS unit (row, u) holds global unit (row, u ^ (row&7)).
    const int srow  = wv * 4 + (lane >> 4);               // row base within 16-row group
    const int sunit = (lane & 15) ^ (srow & 7);           // swizzled source unit
    const u16* Bsrc = xnb + (size_t)srow * D + sunit * 8; // + jbase*D + rnd*16*D
    u16* BsDst = (u16*)Bs + wv * 512;                     // wave-uniform; + rnd*2048

    // --- read geometry ---
    const int swz7 = m0 & 7;
    int koff[4];
    #pragma unroll
    for (int kk = 0; kk < 4; kk++) koff[kk] = ((kq + kk * 4) ^ swz7) * 8;
    const u16* LBrd = (const u16*)Bs + m0 * 128;          // + c*4096 + tn*2048 + koff

    float dacc[2][4] = {};
    float nacc[2][4] = {};
    float4v acc[2][2];
    short8 bc[4][2];

    for (int q = 0; q < JQ; q++) {
        const int jt = jt0 + q;
        const int jbase = jt * TILE;
        const bool diag = (jt == blockIdx.x);

        __syncthreads();                 // Bs free (q=0: also orders Ms writes)
        {   // stage B tile jt: 8 rounds x (256 thr x 16B) = 32 KB
            const u16* sq = Bsrc + (size_t)jbase * D;
            #pragma unroll
            for (int rnd = 0; rnd < 8; rnd++)
                load_lds16(sq + rnd * 16 * D, BsDst + rnd * 2048);
        }
        __syncthreads();                 // staging complete (barrier drains vmcnt)

        // chunk 0 fragments
        #pragma unroll
        for (int kk = 0; kk < 4; kk++)
            #pragma unroll
            for (int tn = 0; tn < 2; tn++)
                bc[kk][tn] = *(const short8*)(LBrd + tn * 2048 + koff[kk]);

        mfma_chunk<true>(acc, a_f, bc, LBrd + 1 * 4096, koff);
        if (diag) epi_chunk<true , 0>(acc, Ms, dacc, nacc, wv, kq, m0, ibase, jbase, q, kA2, kB2);
        else      epi_chunk<false, 0>(acc, Ms, dacc, nacc, wv, kq, m0, ibase, jbase, q, kA2, kB2);

        mfma_chunk<true>(acc, a_f, bc, LBrd + 2 * 4096, koff);
        if (diag) epi_chunk<true , 1>(acc, Ms, dacc, nacc, wv, kq, m0, ibase, jbase, q, kA2, kB2);
        else      epi_chunk<false, 1>(acc, Ms, dacc, nacc, wv, kq, m0, ibase, jbase, q, kA2, kB2);

        mfma_chunk<true>(acc, a_f, bc, LBrd + 3 * 4096, koff);
        if (diag) epi_chunk<true , 2>(acc, Ms, dacc, nacc, wv, kq, m0, ibase, jbase, q, kA2, kB2);
        else      epi_chunk<false, 2>(acc, Ms, dacc, nacc, wv, kq, m0, ibase, jbase, q, kA2, kB2);

        mfma_chunk<false>(acc, a_f, bc, LBrd, koff);
        if (diag) epi_chunk<true , 3>(acc, Ms, dacc, nacc, wv, kq, m0, ibase, jbase, q, kA2, kB2);
        else      epi_chunk<false, 3>(acc, Ms, dacc, nacc, wv, kq, m0, ibase, jbase, q, kA2, kB2);
    }

    // reduce across the 16 column-lanes, then atomics
    #pragma unroll
    for (int tm = 0; tm < 2; tm++) {
        #pragma unroll
        for (int r = 0; r < 4; r++) {
            float d = dacc[tm][r], n = nacc[tm][r];
            #pragma unroll
            for (int off = 1; off < 16; off <<= 1) {
                d += __shfl_xor(d, off);
                n += __shfl_xor(n, off);
            }
            if (m0 == 0) {
                const int gi = ibase + wv * 32 + tm * 16 + kq * 4 + r;
                atomicAdd(&den[gi], d);
                atomicAdd(&num[gi], n);
            }
        }
    }
}

// ---------------------------------------------------------------------------
// Kernel 3: final loss = mean_i -log(T * (p_i + num_i) / (p_i + den_i))
// ---------------------------------------------------------------------------
__global__ void loss_kernel(const float* __restrict__ p, const float* __restrict__ den,
                            const float* __restrict__ num, float* __restrict__ out,
                            const float* __restrict__ tp) {
    __shared__ float red[16];
    const float T = tp[0];
    float s = 0.0f;
    #pragma unroll
    for (int t = 0; t < N / 1024; t++) {
        const int i = t * 1024 + threadIdx.x;
        float pi = p[i];
        s += -__logf(T * (pi + num[i]) / (pi + den[i]));
    }
    #pragma unroll
    for (int off = 32; off; off >>= 1) s += __shfl_xor(s, off);
    const int lane = threadIdx.x & 63, wv = threadIdx.x >> 6;
    if (lane == 0) red[wv] = s;
    __syncthreads();
    if (wv == 0) {
        float t = (lane < 16) ? red[lane] : 0.0f;
        #pragma unroll
        for (int off = 8; off; off >>= 1) t += __shfl_xor(t, off);
        if (lane == 0) out[0] = t / (float)N;
    }
}

// ---------------------------------------------------------------------------
extern "C" void kernel_launch(void* const* d_in, const int* in_sizes, int n_in,
                              void* d_out, int out_size, void* d_ws, size_t ws_size,
                              hipStream_t stream) {
    (void)in_sizes; (void)n_in; (void)out_size; (void)ws_size;
    const float* inst   = (const float*)d_in[0];
    const float* proxy  = (const float*)d_in[1];
    const float* nm     = (const float*)d_in[2];
    const int*   labels = (const int*)d_in[3];
    const float* temp   = (const float*)d_in[4];
    const float* marg   = (const float*)d_in[5];
    float* out = (float*)d_out;

    char* ws = (char*)d_ws;
    u16*   xnb    = (u16*)ws;                         // N*D*2      = 2,097,152 B
    float* p_arr  = (float*)(ws + 2097152);           // N*4        = 32,768 B
    u64*   packed = (u64*)(ws + 2129920);             // C*128*8    = 1,024,000 B
    float* den    = (float*)(ws + 3153920);           // N*4
    float* num    = (float*)(ws + 3186688);           // N*4

    prep_kernel<<<4096, 256, 0, stream>>>(nm, packed, inst, proxy, xnb, p_arr,
                                          den, num, temp, marg);
    cc_main<<<dim3(N / TILE, GRIDY), 256, 0, stream>>>(xnb, labels, packed, den, num, temp, marg);
    loss_kernel<<<1, 1024, 0, stream>>>(p_arr, den, num, out, temp);
}